// Round 5
// baseline (798.337 us; speedup 1.0000x reference)
//
#include <hip/hip_runtime.h>
#include <hip/hip_fp16.h>

// GCN 2-layer forward on MI355X (gfx950).
// conv(x,W,b)[v] = dinv[v]*( sum_{(u,v)} g[u] + g[v] ) + b,  g[u]=dinv[u]*(x[u]@W)
// gemm1 = MFMA bf16 3-term split (~fp32 accuracy); aggregation = CSR gather with
// fp16 message buffers (halved gather bytes); layer-2 GEMM fused into gather1;
// log_softmax fused into gather2. 7 launches total.

#define IN_DIM 512
#define HID    64
#define OUTD   32

typedef __attribute__((ext_vector_type(8))) short bf16x8;
typedef __attribute__((ext_vector_type(4))) float floatx4;
typedef __attribute__((ext_vector_type(4))) unsigned short ushort4v;
typedef __attribute__((ext_vector_type(8))) unsigned short ushort8v;

__device__ __forceinline__ unsigned short f2bf(float f) {
    unsigned int u = __float_as_uint(f);
    unsigned int r = (u + 0x7fffu + ((u >> 16) & 1u)) >> 16;
    return (unsigned short)r;
}
__device__ __forceinline__ float bf2f(unsigned short h) {
    return __uint_as_float(((unsigned int)h) << 16);
}

__device__ __forceinline__ int eidx(const int* idx32, long long e, int is64) {
    if (is64) { const long long* p = (const long long*)idx32; return (int)p[e]; }
    return idx32[e];
}

// --- fused init: cnt zero + int64 detect + W1 transpose/split ----------------
__global__ void k_init(const float* __restrict__ W1,
                       unsigned short* __restrict__ W1t_hi,
                       unsigned short* __restrict__ W1t_lo,
                       const int* __restrict__ idx, int* __restrict__ flag,
                       int* __restrict__ cnt, int N) {
    int t = blockIdx.x * blockDim.x + threadIdx.x;
    if (t == 0) {
        int z = (idx[1] == 0) & (idx[3] == 0) & (idx[5] == 0) & (idx[7] == 0);
        *flag = z;
    }
    if (t < N) cnt[t] = 0;
    if (t < 64 * 512) {
        int n = t >> 9, k = t & 511;
        float v = W1[k * HID + n];
        unsigned short h = f2bf(v);
        W1t_hi[t] = h;
        W1t_lo[t] = f2bf(v - bf2f(h));
    }
}

__global__ void k_count(const int* __restrict__ idx, const int* __restrict__ flag,
                        int* __restrict__ cnt, int E) {
    int e = blockIdx.x * blockDim.x + threadIdx.x;
    if (e >= E) return;
    const int is64 = *flag;
    int c = eidx(idx, (long long)E + e, is64);
    atomicAdd(&cnt[c], 1);
}

// --- single-WG scan: rowptr = exscan(cnt); dinv = rsqrt(1+cnt) ---------------
__global__ void k_scan1wg(const int* __restrict__ cnt, int* __restrict__ rowptr,
                          float* __restrict__ dinv, int N, int E) {
    __shared__ int s[1024];
    const int t = threadIdx.x;
    const int chunk = (N + 1023) / 1024;
    const int lo = t * chunk;
    const int hi = (lo + chunk < N) ? lo + chunk : N;
    int sum = 0;
    for (int i = lo; i < hi; ++i) sum += cnt[i];
    s[t] = sum;
    __syncthreads();
#pragma unroll
    for (int off = 1; off < 1024; off <<= 1) {
        int x = (t >= off) ? s[t - off] : 0;
        __syncthreads();
        s[t] += x;
        __syncthreads();
    }
    int run = s[t] - sum;              // exclusive prefix of this chunk
    for (int i = lo; i < hi; ++i) {
        int c = cnt[i];
        rowptr[i] = run;
        dinv[i] = rsqrtf((float)(1 + c));
        run += c;
    }
    if (t == 0) rowptr[N] = E;
}

__global__ void k_place(const int* __restrict__ idx, const int* __restrict__ flag,
                        int* __restrict__ cnt, const int* __restrict__ rowptr,
                        int* __restrict__ src, int E) {
    int e = blockIdx.x * blockDim.x + threadIdx.x;
    if (e >= E) return;
    const int is64 = *flag;
    int r = eidx(idx, e, is64);
    int c = eidx(idx, (long long)E + e, is64);
    int ofs = atomicAdd(&cnt[c], -1) - 1;
    src[rowptr[c] + ofs] = r;
}

// --- layer-1 GEMM via MFMA: g1[r][j] = fp16( dinv[r]*(x[r]@W1)[j] ) ----------
__launch_bounds__(256)
__global__ void k_gemm1_mfma(const float* __restrict__ x,
                             const unsigned short* __restrict__ Wt_hi,
                             const unsigned short* __restrict__ Wt_lo,
                             const float* __restrict__ dinv,
                             __half* __restrict__ g1, int N) {
    __shared__ unsigned short xs_hi[64 * 72];
    __shared__ unsigned short xs_lo[64 * 72];
    __shared__ unsigned short ws_hi[64 * 72];
    __shared__ unsigned short ws_lo[64 * 72];

    const int t = threadIdx.x;
    const int lane = t & 63;
    const int w = t >> 6;
    const int m = lane & 15;
    const int quad = lane >> 4;
    const int row_base = blockIdx.x * 64;

    const floatx4 zero = {0.0f, 0.0f, 0.0f, 0.0f};
    floatx4 acc[4] = {zero, zero, zero, zero};

    for (int kc = 0; kc < IN_DIM; kc += 64) {
        {   // stage x: 64 rows x 64 k -> bf16 hi/lo
            const int kq = (t & 15) * 4;
#pragma unroll
            for (int p = 0; p < 4; ++p) {
                int rl = (t >> 4) + p * 16;
                int row = row_base + rl;
                if (row > N - 1) row = N - 1;
                float4 v = *(const float4*)(x + (size_t)row * IN_DIM + kc + kq);
                ushort4v hi, lo;
                hi.x = f2bf(v.x); lo.x = f2bf(v.x - bf2f(hi.x));
                hi.y = f2bf(v.y); lo.y = f2bf(v.y - bf2f(hi.y));
                hi.z = f2bf(v.z); lo.z = f2bf(v.z - bf2f(hi.z));
                hi.w = f2bf(v.w); lo.w = f2bf(v.w - bf2f(hi.w));
                *(ushort4v*)&xs_hi[rl * 72 + kq] = hi;
                *(ushort4v*)&xs_lo[rl * 72 + kq] = lo;
            }
        }
        {   // stage W: 64 n x 64 k (each thread 1 n x 16 k, 2x ushort8v per plane)
            const int nl = t >> 2;
            const int q = (t & 3) * 16;
            const unsigned short* ph = Wt_hi + (size_t)nl * IN_DIM + kc + q;
            const unsigned short* pl = Wt_lo + (size_t)nl * IN_DIM + kc + q;
            *(ushort8v*)&ws_hi[nl * 72 + q]     = *(const ushort8v*)(ph);
            *(ushort8v*)&ws_hi[nl * 72 + q + 8] = *(const ushort8v*)(ph + 8);
            *(ushort8v*)&ws_lo[nl * 72 + q]     = *(const ushort8v*)(pl);
            *(ushort8v*)&ws_lo[nl * 72 + q + 8] = *(const ushort8v*)(pl + 8);
        }
        __syncthreads();
#pragma unroll
        for (int ks = 0; ks < 2; ++ks) {
            const int ko = ks * 32 + quad * 8;
            bf16x8 a_hi = *(const bf16x8*)&xs_hi[(w * 16 + m) * 72 + ko];
            bf16x8 a_lo = *(const bf16x8*)&xs_lo[(w * 16 + m) * 72 + ko];
#pragma unroll
            for (int nt = 0; nt < 4; ++nt) {
                bf16x8 b_hi = *(const bf16x8*)&ws_hi[(nt * 16 + m) * 72 + ko];
                bf16x8 b_lo = *(const bf16x8*)&ws_lo[(nt * 16 + m) * 72 + ko];
                acc[nt] = __builtin_amdgcn_mfma_f32_16x16x32_bf16(a_hi, b_hi, acc[nt], 0, 0, 0);
                acc[nt] = __builtin_amdgcn_mfma_f32_16x16x32_bf16(a_lo, b_hi, acc[nt], 0, 0, 0);
                acc[nt] = __builtin_amdgcn_mfma_f32_16x16x32_bf16(a_hi, b_lo, acc[nt], 0, 0, 0);
            }
        }
        __syncthreads();
    }
    // D layout: col = lane&15, row = quad*4 + r
#pragma unroll
    for (int r = 0; r < 4; ++r) {
        const int row = row_base + w * 16 + quad * 4 + r;
        if (row < N) {
            const float dv = dinv[row];
#pragma unroll
            for (int nt = 0; nt < 4; ++nt)
                g1[(size_t)row * HID + nt * 16 + m] = __float2half(acc[nt][r] * dv);
        }
    }
}

// --- fused layer-1 aggregate + layer-2 GEMM ----------------------------------
// wave per node v: a1[j] = g1[v][j] + sum_in g1[src][j]; h = relu(dinv*a1 + b1);
// g2[v][:] = fp16( dinv * (h @ W2) ). fp16 gather rows = 128 B/edge.
__launch_bounds__(256)
__global__ void k_agg1_gemm2(const int* __restrict__ rowptr, const int* __restrict__ src,
                             const __half* __restrict__ g1, const float* __restrict__ W2,
                             const float* __restrict__ b1, const float* __restrict__ dinv,
                             __half* __restrict__ g2, int N) {
    __shared__ float w2s[HID * OUTD];   // 8 KB
    __shared__ float hs[4][HID];

    const int t = threadIdx.x;
    for (int i = t; i < HID * OUTD; i += 256) w2s[i] = W2[i];

    const int w = t >> 6, lane = t & 63;
    const int v = blockIdx.x * 4 + w;
    float dv = 0.0f;
    if (v < N) {
        float acc = (float)g1[(size_t)v * HID + lane];   // self-loop
        int i = rowptr[v];
        const int end = rowptr[v + 1];
        for (; i + 3 < end; i += 4) {                     // 4-deep ILP
            int r0 = src[i], r1 = src[i + 1], r2 = src[i + 2], r3 = src[i + 3];
            float a0 = (float)g1[(size_t)r0 * HID + lane];
            float a1 = (float)g1[(size_t)r1 * HID + lane];
            float a2 = (float)g1[(size_t)r2 * HID + lane];
            float a3 = (float)g1[(size_t)r3 * HID + lane];
            acc += (a0 + a1) + (a2 + a3);
        }
        for (; i < end; ++i) acc += (float)g1[(size_t)src[i] * HID + lane];
        dv = dinv[v];
        hs[w][lane] = fmaxf(fmaf(dv, acc, b1[lane]), 0.0f);
    }
    __syncthreads();   // covers w2s staging AND hs rows
    if (v < N) {
        const int j = lane & 31, half = lane >> 5;
        float s = 0.0f;
#pragma unroll
        for (int k = 0; k < 32; ++k) {
            const int kk = half * 32 + k;
            s = fmaf(hs[w][kk], w2s[kk * OUTD + j], s);
        }
        s += __shfl_down(s, 32);
        if (lane < 32) g2[(size_t)v * OUTD + j] = __float2half(s * dv);
    }
}

// --- fused layer-2 aggregate + bias + log_softmax ----------------------------
__global__ void k_out(const int* __restrict__ rowptr, const int* __restrict__ src,
                      const __half* __restrict__ g2, const float* __restrict__ b2,
                      const float* __restrict__ dinv, float* __restrict__ out, int N) {
    const int v = blockIdx.x * 8 + (int)(threadIdx.x >> 5);
    const int j = threadIdx.x & 31;
    if (v >= N) return;
    float acc = (float)g2[(size_t)v * OUTD + j];   // self-loop
    int i = rowptr[v];
    const int end = rowptr[v + 1];
    for (; i + 3 < end; i += 4) {
        int r0 = src[i], r1 = src[i + 1], r2 = src[i + 2], r3 = src[i + 3];
        float a0 = (float)g2[(size_t)r0 * OUTD + j];
        float a1 = (float)g2[(size_t)r1 * OUTD + j];
        float a2 = (float)g2[(size_t)r2 * OUTD + j];
        float a3 = (float)g2[(size_t)r3 * OUTD + j];
        acc += (a0 + a1) + (a2 + a3);
    }
    for (; i < end; ++i) acc += (float)g2[(size_t)src[i] * OUTD + j];
    const float z = fmaf(dinv[v], acc, b2[j]);
    float m = z;
#pragma unroll
    for (int d = 16; d; d >>= 1) m = fmaxf(m, __shfl_xor(m, d, 32));
    float s = expf(z - m);
#pragma unroll
    for (int d = 16; d; d >>= 1) s += __shfl_xor(s, d, 32);
    out[(size_t)v * OUTD + j] = z - m - logf(s);
}

extern "C" void kernel_launch(void* const* d_in, const int* in_sizes, int n_in,
                              void* d_out, int out_size, void* d_ws, size_t ws_size,
                              hipStream_t stream) {
    const float* x   = (const float*)d_in[0];
    const int*   idx = (const int*)d_in[1];
    const float* W1  = (const float*)d_in[2];
    const float* b1  = (const float*)d_in[3];
    const float* W2  = (const float*)d_in[4];
    const float* b2  = (const float*)d_in[5];
    float* out = (float*)d_out;

    const int N = in_sizes[0] / IN_DIM;      // 100000
    const int E = in_sizes[1] / 2;           // 1600000

    // ---- workspace layout ----
    unsigned short* W1t_hi = (unsigned short*)d_ws;        // 64*512
    unsigned short* W1t_lo = W1t_hi + 64 * 512;
    int* cnt    = (int*)(W1t_lo + 64 * 512);               // N
    int* rowptr = cnt + N;                                 // N+4
    int* srcA   = rowptr + (N + 4);                        // E
    int* flag   = srcA + E;                                // 4
    float* dinv = (float*)(flag + 4);                      // N
    __half* g1  = (__half*)(dinv + N);                     // 64N halves
    __half* g2  = g1 + (size_t)N * HID;                    // 32N halves

    const int B = 256;

    k_init<<<(N + B - 1) / B, B, 0, stream>>>(W1, W1t_hi, W1t_lo, idx, flag, cnt, N);
    k_count<<<(E + B - 1) / B, B, 0, stream>>>(idx, flag, cnt, E);
    k_scan1wg<<<1, 1024, 0, stream>>>(cnt, rowptr, dinv, N, E);
    k_place<<<(E + B - 1) / B, B, 0, stream>>>(idx, flag, cnt, rowptr, srcA, E);

    k_gemm1_mfma<<<(N + 63) / 64, 256, 0, stream>>>(x, W1t_hi, W1t_lo, dinv, g1, N);
    k_agg1_gemm2<<<(N + 3) / 4, 256, 0, stream>>>(rowptr, srcA, g1, W2, b1, dinv, g2, N);
    k_out<<<(N + 7) / 8, B, 0, stream>>>(rowptr, srcA, g2, b2, dinv, out, N);
}

// Round 6
// 587.645 us; speedup vs baseline: 1.3585x; 1.3585x over previous
//
#include <hip/hip_runtime.h>
#include <hip/hip_fp16.h>

// GCN 2-layer forward on MI355X (gfx950).
// conv(x,W,b)[v] = dinv[v]*( sum_{(u,v)} g[u] + g[v] ) + b,  g[u]=dinv[u]*(x[u]@W)
// gemm1 = MFMA bf16 3-term split (~fp32 accuracy); aggregation = CSR gather with
// fp16 message buffers; layer-2 GEMM fused into gather1; log_softmax fused into
// gather2. Parallel 3-kernel scan (round-5's single-WG scan was 226us latency-bound).

#define IN_DIM 512
#define HID    64
#define OUTD   32

typedef __attribute__((ext_vector_type(8))) short bf16x8;
typedef __attribute__((ext_vector_type(4))) float floatx4;
typedef __attribute__((ext_vector_type(4))) unsigned short ushort4v;
typedef __attribute__((ext_vector_type(8))) unsigned short ushort8v;

__device__ __forceinline__ unsigned short f2bf(float f) {
    unsigned int u = __float_as_uint(f);
    unsigned int r = (u + 0x7fffu + ((u >> 16) & 1u)) >> 16;
    return (unsigned short)r;
}
__device__ __forceinline__ float bf2f(unsigned short h) {
    return __uint_as_float(((unsigned int)h) << 16);
}

__device__ __forceinline__ int eidx(const int* idx32, long long e, int is64) {
    if (is64) { const long long* p = (const long long*)idx32; return (int)p[e]; }
    return idx32[e];
}

// --- fused init: cnt zero + int64 detect + W1 transpose/split ----------------
__global__ void k_init(const float* __restrict__ W1,
                       unsigned short* __restrict__ W1t_hi,
                       unsigned short* __restrict__ W1t_lo,
                       const int* __restrict__ idx, int* __restrict__ flag,
                       int* __restrict__ cnt, int N) {
    int t = blockIdx.x * blockDim.x + threadIdx.x;
    if (t == 0) {
        int z = (idx[1] == 0) & (idx[3] == 0) & (idx[5] == 0) & (idx[7] == 0);
        *flag = z;
    }
    if (t < N) cnt[t] = 0;
    if (t < 64 * 512) {
        int n = t >> 9, k = t & 511;
        float v = W1[k * HID + n];
        unsigned short h = f2bf(v);
        W1t_hi[t] = h;
        W1t_lo[t] = f2bf(v - bf2f(h));
    }
}

__global__ void k_count(const int* __restrict__ idx, const int* __restrict__ flag,
                        int* __restrict__ cnt, int E) {
    int e = blockIdx.x * blockDim.x + threadIdx.x;
    if (e >= E) return;
    const int is64 = *flag;
    int c = eidx(idx, (long long)E + e, is64);
    atomicAdd(&cnt[c], 1);
}

// --- parallel 3-kernel exclusive scan; dinv folded into scanA ----------------
__global__ void k_scanA(const int* __restrict__ cnt, int* __restrict__ rowptr,
                        int* __restrict__ part, float* __restrict__ dinv, int N) {
    __shared__ int s[256];
    const int t = threadIdx.x;
    const int i = blockIdx.x * 256 + t;
    int v = (i < N) ? cnt[i] : 0;
    if (i < N) dinv[i] = rsqrtf((float)(1 + v));
    s[t] = v;
    __syncthreads();
#pragma unroll
    for (int off = 1; off < 256; off <<= 1) {
        int x = (t >= off) ? s[t - off] : 0;
        __syncthreads();
        s[t] += x;
        __syncthreads();
    }
    if (i < N) rowptr[i] = s[t] - v;
    if (t == 255) part[blockIdx.x] = s[255];
}

__global__ void k_scanB(const int* __restrict__ part, int* __restrict__ partex, int nb) {
    __shared__ int s[1024];
    const int t = threadIdx.x;
    int v = (t < nb) ? part[t] : 0;
    s[t] = v;
    __syncthreads();
#pragma unroll
    for (int off = 1; off < 1024; off <<= 1) {
        int x = (t >= off) ? s[t - off] : 0;
        __syncthreads();
        s[t] += x;
        __syncthreads();
    }
    partex[t] = s[t] - v;
}

__global__ void k_scanC(int* __restrict__ rowptr, const int* __restrict__ partex,
                        int N, int E) {
    const int i = blockIdx.x * blockDim.x + threadIdx.x;
    if (i < N) rowptr[i] += partex[i >> 8];
    if (i == 0) rowptr[N] = E;
}

__global__ void k_place(const int* __restrict__ idx, const int* __restrict__ flag,
                        int* __restrict__ cnt, const int* __restrict__ rowptr,
                        int* __restrict__ src, int E) {
    int e = blockIdx.x * blockDim.x + threadIdx.x;
    if (e >= E) return;
    const int is64 = *flag;
    int r = eidx(idx, e, is64);
    int c = eidx(idx, (long long)E + e, is64);
    int ofs = atomicAdd(&cnt[c], -1) - 1;
    src[rowptr[c] + ofs] = r;
}

// --- layer-1 GEMM via MFMA: g1[r][j] = fp16( dinv[r]*(x[r]@W1)[j] ) ----------
__launch_bounds__(256)
__global__ void k_gemm1_mfma(const float* __restrict__ x,
                             const unsigned short* __restrict__ Wt_hi,
                             const unsigned short* __restrict__ Wt_lo,
                             const float* __restrict__ dinv,
                             __half* __restrict__ g1, int N) {
    __shared__ unsigned short xs_hi[64 * 72];
    __shared__ unsigned short xs_lo[64 * 72];
    __shared__ unsigned short ws_hi[64 * 72];
    __shared__ unsigned short ws_lo[64 * 72];

    const int t = threadIdx.x;
    const int lane = t & 63;
    const int w = t >> 6;
    const int m = lane & 15;
    const int quad = lane >> 4;
    const int row_base = blockIdx.x * 64;

    const floatx4 zero = {0.0f, 0.0f, 0.0f, 0.0f};
    floatx4 acc[4] = {zero, zero, zero, zero};

    for (int kc = 0; kc < IN_DIM; kc += 64) {
        {   // stage x: 64 rows x 64 k -> bf16 hi/lo
            const int kq = (t & 15) * 4;
#pragma unroll
            for (int p = 0; p < 4; ++p) {
                int rl = (t >> 4) + p * 16;
                int row = row_base + rl;
                if (row > N - 1) row = N - 1;
                float4 v = *(const float4*)(x + (size_t)row * IN_DIM + kc + kq);
                ushort4v hi, lo;
                hi.x = f2bf(v.x); lo.x = f2bf(v.x - bf2f(hi.x));
                hi.y = f2bf(v.y); lo.y = f2bf(v.y - bf2f(hi.y));
                hi.z = f2bf(v.z); lo.z = f2bf(v.z - bf2f(hi.z));
                hi.w = f2bf(v.w); lo.w = f2bf(v.w - bf2f(hi.w));
                *(ushort4v*)&xs_hi[rl * 72 + kq] = hi;
                *(ushort4v*)&xs_lo[rl * 72 + kq] = lo;
            }
        }
        {   // stage W: 64 n x 64 k (each thread 1 n x 16 k, 2x ushort8v per plane)
            const int nl = t >> 2;
            const int q = (t & 3) * 16;
            const unsigned short* ph = Wt_hi + (size_t)nl * IN_DIM + kc + q;
            const unsigned short* pl = Wt_lo + (size_t)nl * IN_DIM + kc + q;
            *(ushort8v*)&ws_hi[nl * 72 + q]     = *(const ushort8v*)(ph);
            *(ushort8v*)&ws_hi[nl * 72 + q + 8] = *(const ushort8v*)(ph + 8);
            *(ushort8v*)&ws_lo[nl * 72 + q]     = *(const ushort8v*)(pl);
            *(ushort8v*)&ws_lo[nl * 72 + q + 8] = *(const ushort8v*)(pl + 8);
        }
        __syncthreads();
#pragma unroll
        for (int ks = 0; ks < 2; ++ks) {
            const int ko = ks * 32 + quad * 8;
            bf16x8 a_hi = *(const bf16x8*)&xs_hi[(w * 16 + m) * 72 + ko];
            bf16x8 a_lo = *(const bf16x8*)&xs_lo[(w * 16 + m) * 72 + ko];
#pragma unroll
            for (int nt = 0; nt < 4; ++nt) {
                bf16x8 b_hi = *(const bf16x8*)&ws_hi[(nt * 16 + m) * 72 + ko];
                bf16x8 b_lo = *(const bf16x8*)&ws_lo[(nt * 16 + m) * 72 + ko];
                acc[nt] = __builtin_amdgcn_mfma_f32_16x16x32_bf16(a_hi, b_hi, acc[nt], 0, 0, 0);
                acc[nt] = __builtin_amdgcn_mfma_f32_16x16x32_bf16(a_lo, b_hi, acc[nt], 0, 0, 0);
                acc[nt] = __builtin_amdgcn_mfma_f32_16x16x32_bf16(a_hi, b_lo, acc[nt], 0, 0, 0);
            }
        }
        __syncthreads();
    }
    // D layout: col = lane&15, row = quad*4 + r
#pragma unroll
    for (int r = 0; r < 4; ++r) {
        const int row = row_base + w * 16 + quad * 4 + r;
        if (row < N) {
            const float dv = dinv[row];
#pragma unroll
            for (int nt = 0; nt < 4; ++nt)
                g1[(size_t)row * HID + nt * 16 + m] = __float2half(acc[nt][r] * dv);
        }
    }
}

// --- fused layer-1 aggregate + layer-2 GEMM ----------------------------------
__launch_bounds__(256)
__global__ void k_agg1_gemm2(const int* __restrict__ rowptr, const int* __restrict__ src,
                             const __half* __restrict__ g1, const float* __restrict__ W2,
                             const float* __restrict__ b1, const float* __restrict__ dinv,
                             __half* __restrict__ g2, int N) {
    __shared__ float w2s[HID * OUTD];   // 8 KB
    __shared__ float hs[4][HID];

    const int t = threadIdx.x;
    for (int i = t; i < HID * OUTD; i += 256) w2s[i] = W2[i];

    const int w = t >> 6, lane = t & 63;
    const int v = blockIdx.x * 4 + w;
    float dv = 0.0f;
    if (v < N) {
        float acc = (float)g1[(size_t)v * HID + lane];   // self-loop
        int i = rowptr[v];
        const int end = rowptr[v + 1];
        for (; i + 3 < end; i += 4) {                     // 4-deep ILP
            int r0 = src[i], r1 = src[i + 1], r2 = src[i + 2], r3 = src[i + 3];
            float a0 = (float)g1[(size_t)r0 * HID + lane];
            float a1 = (float)g1[(size_t)r1 * HID + lane];
            float a2 = (float)g1[(size_t)r2 * HID + lane];
            float a3 = (float)g1[(size_t)r3 * HID + lane];
            acc += (a0 + a1) + (a2 + a3);
        }
        for (; i < end; ++i) acc += (float)g1[(size_t)src[i] * HID + lane];
        dv = dinv[v];
        hs[w][lane] = fmaxf(fmaf(dv, acc, b1[lane]), 0.0f);
    }
    __syncthreads();   // covers w2s staging AND hs rows
    if (v < N) {
        const int j = lane & 31, half = lane >> 5;
        float s = 0.0f;
#pragma unroll
        for (int k = 0; k < 32; ++k) {
            const int kk = half * 32 + k;
            s = fmaf(hs[w][kk], w2s[kk * OUTD + j], s);
        }
        s += __shfl_down(s, 32);
        if (lane < 32) g2[(size_t)v * OUTD + j] = __float2half(s * dv);
    }
}

// --- fused layer-2 aggregate + bias + log_softmax ----------------------------
__global__ void k_out(const int* __restrict__ rowptr, const int* __restrict__ src,
                      const __half* __restrict__ g2, const float* __restrict__ b2,
                      const float* __restrict__ dinv, float* __restrict__ out, int N) {
    const int v = blockIdx.x * 8 + (int)(threadIdx.x >> 5);
    const int j = threadIdx.x & 31;
    if (v >= N) return;
    float acc = (float)g2[(size_t)v * OUTD + j];   // self-loop
    int i = rowptr[v];
    const int end = rowptr[v + 1];
    for (; i + 3 < end; i += 4) {
        int r0 = src[i], r1 = src[i + 1], r2 = src[i + 2], r3 = src[i + 3];
        float a0 = (float)g2[(size_t)r0 * OUTD + j];
        float a1 = (float)g2[(size_t)r1 * OUTD + j];
        float a2 = (float)g2[(size_t)r2 * OUTD + j];
        float a3 = (float)g2[(size_t)r3 * OUTD + j];
        acc += (a0 + a1) + (a2 + a3);
    }
    for (; i < end; ++i) acc += (float)g2[(size_t)src[i] * OUTD + j];
    const float z = fmaf(dinv[v], acc, b2[j]);
    float m = z;
#pragma unroll
    for (int d = 16; d; d >>= 1) m = fmaxf(m, __shfl_xor(m, d, 32));
    float s = expf(z - m);
#pragma unroll
    for (int d = 16; d; d >>= 1) s += __shfl_xor(s, d, 32);
    out[(size_t)v * OUTD + j] = z - m - logf(s);
}

extern "C" void kernel_launch(void* const* d_in, const int* in_sizes, int n_in,
                              void* d_out, int out_size, void* d_ws, size_t ws_size,
                              hipStream_t stream) {
    const float* x   = (const float*)d_in[0];
    const int*   idx = (const int*)d_in[1];
    const float* W1  = (const float*)d_in[2];
    const float* b1  = (const float*)d_in[3];
    const float* W2  = (const float*)d_in[4];
    const float* b2  = (const float*)d_in[5];
    float* out = (float*)d_out;

    const int N = in_sizes[0] / IN_DIM;      // 100000
    const int E = in_sizes[1] / 2;           // 1600000

    // ---- workspace layout ----
    unsigned short* W1t_hi = (unsigned short*)d_ws;        // 64*512
    unsigned short* W1t_lo = W1t_hi + 64 * 512;
    int* cnt    = (int*)(W1t_lo + 64 * 512);               // N
    int* rowptr = cnt + N;                                 // N+4
    int* part   = rowptr + (N + 4);                        // 1024
    int* partex = part + 1024;                             // 1024
    int* srcA   = partex + 1024;                           // E
    int* flag   = srcA + E;                                // 4
    float* dinv = (float*)(flag + 4);                      // N
    __half* g1  = (__half*)(dinv + N);                     // 64N halves
    __half* g2  = g1 + (size_t)N * HID;                    // 32N halves

    const int B = 256;
    const int nb = (N + 255) / 256;

    k_init<<<(N + B - 1) / B, B, 0, stream>>>(W1, W1t_hi, W1t_lo, idx, flag, cnt, N);
    k_count<<<(E + B - 1) / B, B, 0, stream>>>(idx, flag, cnt, E);
    k_scanA<<<nb, 256, 0, stream>>>(cnt, rowptr, part, dinv, N);
    k_scanB<<<1, 1024, 0, stream>>>(part, partex, nb);
    k_scanC<<<nb, 256, 0, stream>>>(rowptr, partex, N, E);
    k_place<<<(E + B - 1) / B, B, 0, stream>>>(idx, flag, cnt, rowptr, srcA, E);

    k_gemm1_mfma<<<(N + 63) / 64, 256, 0, stream>>>(x, W1t_hi, W1t_lo, dinv, g1, N);
    k_agg1_gemm2<<<(N + 3) / 4, 256, 0, stream>>>(rowptr, srcA, g1, W2, b1, dinv, g2, N);
    k_out<<<(N + 7) / 8, B, 0, stream>>>(rowptr, srcA, g2, b2, dinv, out, N);
}